// Round 3
// baseline (793.399 us; speedup 1.0000x reference)
//
#include <hip/hip_runtime.h>
#include <cstdint>
#include <cstddef>

// ---------------------------------------------------------------------------
// AffineMultiQueryHardAttentionEncoder
//   scores[m] = max_n ( (q[n]*a) . k[m] ), top-64, softmax, sum w_i * V[idx_i]
// R3: GEMM -> dbuf 1-ahead pipeline (BM=64,BN=512,BK=32, 2 blocks/CU);
//     histogram select -> multi-block; exact f32 rescore unchanged.
// ---------------------------------------------------------------------------

typedef __attribute__((ext_vector_type(8))) short bf16x8;
typedef __attribute__((ext_vector_type(4))) float f32x4;

static constexpr int NQ = 512;
static constexpr int DD = 1024;
static constexpr int MK = 100000;
static constexpr int BM = 64;
static constexpr int BK = 32;
static constexpr int NKS = DD / BK;                 // 32
static constexpr int MBLOCKS = (MK + BM - 1) / BM;  // 1563
static constexpr int CAP = 1024;

// workspace layout (bytes)
static constexpr size_t QSTAGE_OFF   = 0;                          // [32][512][4][16B] = 1 MiB
static constexpr size_t QSTAGE_BYTES = (size_t)NKS * NQ * 64;
static constexpr size_t SCORES_OFF   = QSTAGE_OFF + QSTAGE_BYTES;
static constexpr size_t SCORES_BYTES = (size_t)MBLOCKS * BM * sizeof(float);
static constexpr size_t CIDX_OFF     = SCORES_OFF + SCORES_BYTES;
static constexpr size_t RESC_OFF     = CIDX_OFF + (size_t)CAP * 4;
static constexpr size_t CNT_OFF      = RESC_OFF + (size_t)CAP * 4;
static constexpr size_t HIST_OFF     = CNT_OFF + 64;
static constexpr size_t VLO_OFF      = HIST_OFF + 8192 * 4;

// LDS: Abuf[2] 64x64B @0/4096, Bbuf[2] 512x64B @8192/40960 -> 73728 B
static constexpr int AOFF = 0;
static constexpr int BOFF = 8192;
static constexpr int GEMM_LDS = 8192 + 2 * 32768;

static __device__ __forceinline__ unsigned short f32_to_bf16_rne(float f) {
    unsigned int u = __float_as_uint(f);
    unsigned int r = (u + 0x7FFFu + ((u >> 16) & 1u)) >> 16;
    return (unsigned short)r;
}
static __device__ __forceinline__ unsigned int xform(float f) {
    unsigned int u = __float_as_uint(f);
    return u ^ ((unsigned int)((int)u >> 31) | 0x80000000u);
}
static __device__ __forceinline__ float unxform(unsigned int u) {
    unsigned int b = (u & 0x80000000u) ? (u ^ 0x80000000u) : ~u;
    return __uint_as_float(b);
}
static __device__ __forceinline__ int swz4(int row) {   // chunk swizzle within 64B row
    return ((row >> 2) ^ row) & 3;
}

typedef __attribute__((address_space(1))) const unsigned int g1u32;
typedef __attribute__((address_space(3))) unsigned int l3u32;
static __device__ __forceinline__ void async16(const void* g, void* l) {
    __builtin_amdgcn_global_load_lds((g1u32*)g, (l3u32*)(uintptr_t)l, 16, 0, 0);
}

// ---------------------------------------------------------------------------
// prep: qa = q*a -> bf16, pre-swizzled: chunk id = (ks*512+row)*4 + c holds
// qa[row][ks*32 + (c ^ swz4(row))*8 .. +7]
// ---------------------------------------------------------------------------
__global__ void prep_q(const float* __restrict__ q, const float* __restrict__ a,
                       unsigned short* __restrict__ qs) {
    int id  = blockIdx.x * 256 + threadIdx.x;   // 0..65535
    int c   = id & 3;
    int row = (id >> 2) & (NQ - 1);
    int ks  = id >> 11;
    int kb  = ks * BK + (c ^ swz4(row)) * 8;

    const float* qrow = q + (size_t)row * DD + kb;
    float4 v0 = *(const float4*)(qrow);
    float4 v1 = *(const float4*)(qrow + 4);
    float4 a0 = *(const float4*)(a + kb);
    float4 a1 = *(const float4*)(a + kb + 4);
    float f[8] = {v0.x * a0.x, v0.y * a0.y, v0.z * a0.z, v0.w * a0.w,
                  v1.x * a1.x, v1.y * a1.y, v1.z * a1.z, v1.w * a1.w};
    bf16x8 o;
#pragma unroll
    for (int j = 0; j < 8; ++j) o[j] = (short)f32_to_bf16_rne(f[j]);
    *(bf16x8*)(qs + (size_t)id * 8) = o;
}

// ---------------------------------------------------------------------------
// prescreen GEMM + column max, double-buffered 1-ahead pipeline
// ---------------------------------------------------------------------------
__launch_bounds__(512, 4)
__global__ void scores_gemm(const float* __restrict__ keys,
                            const unsigned short* __restrict__ qs,
                            float* __restrict__ scores) {
    extern __shared__ char smem[];
    const int tid  = threadIdx.x;
    const int wid  = tid >> 6;
    const int lane = tid & 63;
    const int g    = lane >> 4;
    const int r16  = lane & 15;
    const int m0   = blockIdx.x * BM;

    // A staging: thread -> (row=tid>>3, quad=tid&7); clamp OOB rows
    const int arow = tid >> 3;
    const int ah   = tid & 7;
    int srowA = (m0 + arow < MK) ? (m0 + arow) : (MK - 1);
    const float* aptr = keys + (size_t)srowA * DD + ah * 4;
    const int awbyte = arow * 64 + ((((ah >> 1) ^ swz4(arow)) & 3) << 4) + (ah & 1) * 8;

    // B staging: per-wave 64 rows, linear glds dest; src pre-swizzled
    const char* bsrc = (const char*)qs + (size_t)(wid * 64) * 64 + (size_t)lane * 16;
    const int bdst0 = BOFF + wid * 4096;   // + buf*32768 + j*1024

    // fragment read offsets
    int aoff[4], boff[4];
#pragma unroll
    for (int rt = 0; rt < 4; ++rt) {
        int row = rt * 16 + r16;
        aoff[rt] = row * 64 + (((g ^ swz4(row)) & 3) << 4);
    }
#pragma unroll
    for (int ct = 0; ct < 4; ++ct) {
        int row = wid * 64 + ct * 16 + r16;
        boff[ct] = row * 64 + (((g ^ swz4(row)) & 3) << 4);
    }

    f32x4 acc[4][4] = {};

    // prologue: stage ks=0
#pragma unroll
    for (int j = 0; j < 4; ++j)
        async16(bsrc + j * 1024, smem + bdst0 + j * 1024);
    {
        float4 a0 = *(const float4*)(aptr);
        unsigned long long pk =
            (unsigned long long)f32_to_bf16_rne(a0.x)
          | ((unsigned long long)f32_to_bf16_rne(a0.y) << 16)
          | ((unsigned long long)f32_to_bf16_rne(a0.z) << 32)
          | ((unsigned long long)f32_to_bf16_rne(a0.w) << 48);
        *(unsigned long long*)(smem + AOFF + awbyte) = pk;
    }
    __syncthreads();

    for (int ks = 0; ks < NKS - 1; ++ks) {
        const int cur = ks & 1, nxt = cur ^ 1;
        // ---- prefetch next tile (1-ahead)
#pragma unroll
        for (int j = 0; j < 4; ++j)
            async16(bsrc + (size_t)(ks + 1) * 32768 + j * 1024,
                    smem + bdst0 + nxt * 32768 + j * 1024);
        float4 an = *(const float4*)(aptr + (ks + 1) * BK);

        // ---- compute current
        bf16x8 ah4[4], bh4[4];
#pragma unroll
        for (int rt = 0; rt < 4; ++rt)
            ah4[rt] = *(const bf16x8*)(smem + AOFF + cur * 4096 + aoff[rt]);
#pragma unroll
        for (int ct = 0; ct < 4; ++ct)
            bh4[ct] = *(const bf16x8*)(smem + BOFF + cur * 32768 + boff[ct]);
        __builtin_amdgcn_s_setprio(1);
#pragma unroll
        for (int rt = 0; rt < 4; ++rt)
#pragma unroll
            for (int ct = 0; ct < 4; ++ct)
                acc[rt][ct] = __builtin_amdgcn_mfma_f32_16x16x32_bf16(ah4[rt], bh4[ct], acc[rt][ct], 0, 0, 0);
        __builtin_amdgcn_s_setprio(0);

        // ---- write A(next) late (after MFMA): compiler inserts the vmcnt wait
        unsigned long long pk =
            (unsigned long long)f32_to_bf16_rne(an.x)
          | ((unsigned long long)f32_to_bf16_rne(an.y) << 16)
          | ((unsigned long long)f32_to_bf16_rne(an.z) << 32)
          | ((unsigned long long)f32_to_bf16_rne(an.w) << 48);
        *(unsigned long long*)(smem + AOFF + nxt * 4096 + awbyte) = pk;
        __syncthreads();
    }

    // final K-step (buf 1)
    {
        const int cur = (NKS - 1) & 1;
        bf16x8 ah4[4], bh4[4];
#pragma unroll
        for (int rt = 0; rt < 4; ++rt)
            ah4[rt] = *(const bf16x8*)(smem + AOFF + cur * 4096 + aoff[rt]);
#pragma unroll
        for (int ct = 0; ct < 4; ++ct)
            bh4[ct] = *(const bf16x8*)(smem + BOFF + cur * 32768 + boff[ct]);
#pragma unroll
        for (int rt = 0; rt < 4; ++rt)
#pragma unroll
            for (int ct = 0; ct < 4; ++ct)
                acc[rt][ct] = __builtin_amdgcn_mfma_f32_16x16x32_bf16(ah4[rt], bh4[ct], acc[rt][ct], 0, 0, 0);
    }
    __syncthreads();

    // epilogue: per-lane max over ct, shfl-reduce over 16 query-lanes,
    // cross-wave fold via LDS (reuses Abuf0 region)
    float* wmax = (float*)smem;   // [8][64]
#pragma unroll
    for (int rt = 0; rt < 4; ++rt) {
#pragma unroll
        for (int r = 0; r < 4; ++r) {
            float mx = acc[rt][0][r];
            mx = fmaxf(mx, acc[rt][1][r]);
            mx = fmaxf(mx, acc[rt][2][r]);
            mx = fmaxf(mx, acc[rt][3][r]);
#pragma unroll
            for (int off = 1; off < 16; off <<= 1)
                mx = fmaxf(mx, __shfl_xor(mx, off));
            if (r16 == 0) wmax[wid * 64 + rt * 16 + g * 4 + r] = mx;
        }
    }
    __syncthreads();
    if (tid < BM) {
        float mx = wmax[tid];
#pragma unroll
        for (int w = 1; w < 8; ++w) mx = fmaxf(mx, wmax[w * 64 + tid]);
        int gm = m0 + tid;
        if (gm < MK) scores[gm] = mx;
    }
}

// ---------------------------------------------------------------------------
// threshold select, multi-block
// ---------------------------------------------------------------------------
__global__ void zero_hist(unsigned int* __restrict__ hist, int* __restrict__ cnt) {
    int i = blockIdx.x * 1024 + threadIdx.x;
    if (i < 8192) hist[i] = 0;
    if (i == 0) cnt[0] = 0;
}

__global__ void hist_build(const float* __restrict__ scores, unsigned int* __restrict__ hist) {
    for (int i = blockIdx.x * 256 + threadIdx.x; i < MK; i += gridDim.x * 256)
        atomicAdd(&hist[xform(scores[i]) >> 19], 1u);
}

__launch_bounds__(1024)
__global__ void find_thresh(const unsigned int* __restrict__ hist, float* __restrict__ vlo) {
    __shared__ unsigned int s0[1024], s1[1024];
    const int tid = threadIdx.x;
    unsigned int s = 0;
#pragma unroll
    for (int j = 0; j < 8; ++j) s += hist[tid * 8 + j];
    s0[tid] = s;
    __syncthreads();
    unsigned int* src = s0;
    unsigned int* dst = s1;
    for (int off = 1; off < 1024; off <<= 1) {
        unsigned int v = src[tid] + ((tid + off < 1024) ? src[tid + off] : 0u);
        __syncthreads();   // ensure all reads done before overwriting alt buffer? (dst != src, safe)
        dst[tid] = v;
        __syncthreads();
        unsigned int* t = src; src = dst; dst = t;
    }
    unsigned int suf  = src[tid];
    unsigned int sufn = (tid < 1023) ? src[tid + 1] : 0u;
    if (suf >= 64u && sufn < 64u) {
        unsigned int acc = sufn;
        int b = tid * 8 + 7;
        for (;; --b) { acc += hist[b]; if (acc >= 64u) break; }
        vlo[0] = unxform(((unsigned int)b) << 19) - 1.0f;   // margin 1.0
    }
}

__global__ void collect(const float* __restrict__ scores, const float* __restrict__ vlo,
                        int* __restrict__ cidx, int* __restrict__ cnt) {
    const float t = vlo[0];
    for (int i = blockIdx.x * 256 + threadIdx.x; i < MK; i += gridDim.x * 256) {
        if (scores[i] >= t) {
            int p = atomicAdd(cnt, 1);
            if (p < CAP) cidx[p] = i;
        }
    }
}

// ---------------------------------------------------------------------------
// exact f32 rescore: one block per candidate, max over 512 queries
// ---------------------------------------------------------------------------
__launch_bounds__(256)
__global__ void rescore(const float* __restrict__ q, const float* __restrict__ a,
                        const float* __restrict__ keys,
                        const int* __restrict__ cidx, const int* __restrict__ cnt,
                        float* __restrict__ resc) {
    __shared__ float w[1024];
    __shared__ float smax[4];
    const int b = blockIdx.x;
    if (b >= cnt[0]) return;
    const int m   = cidx[b];
    const int tid = threadIdx.x;

    for (int d = tid; d < 1024; d += 256) w[d] = a[d] * keys[(size_t)m * DD + d];
    __syncthreads();

    const int wid = tid >> 6, lane = tid & 63;
    float best = -__builtin_inff();
    for (int n = wid; n < NQ; n += 4) {
        const float* qr = q + (size_t)n * DD;
        float p = 0.f;
#pragma unroll
        for (int j = 0; j < 4; ++j) {
            float4 v  = *(const float4*)(qr + lane * 4 + 256 * j);
            float4 ww = *(const float4*)(&w[lane * 4 + 256 * j]);
            p += v.x * ww.x + v.y * ww.y + v.z * ww.z + v.w * ww.w;
        }
#pragma unroll
        for (int off = 1; off < 64; off <<= 1) p += __shfl_xor(p, off);
        best = fmaxf(best, p);
    }
    if (lane == 0) smax[wid] = best;
    __syncthreads();
    if (tid == 0)
        resc[b] = fmaxf(fmaxf(smax[0], smax[1]), fmaxf(smax[2], smax[3]));
}

// ---------------------------------------------------------------------------
// final: top-64 over candidates (exact vals, tie: idx asc), softmax, gather V
// ---------------------------------------------------------------------------
__launch_bounds__(256)
__global__ void final_select(const int* __restrict__ cidx, const float* __restrict__ resc,
                             const int* __restrict__ cnt, const float* __restrict__ values,
                             float* __restrict__ out) {
    __shared__ float selw[64];
    __shared__ int   seli[64];
    const int tid = threadIdx.x;
    int nc = cnt[0];
    if (nc > CAP) nc = CAP;

    if (tid < 64) {
        const int lane = tid;
        float lv[16]; int li[16];
#pragma unroll
        for (int j = 0; j < 16; ++j) {
            int slot = lane + 64 * j;
            bool ok = slot < nc;
            lv[j] = ok ? resc[slot] : -__builtin_inff();
            li[j] = ok ? cidx[slot] : 0x7fffffff;
        }
        for (int it = 0; it < 64; ++it) {
            float bv = -__builtin_inff();
            int bg = 0x7fffffff, bj = 0;
#pragma unroll
            for (int j = 0; j < 16; ++j)
                if (lv[j] > bv || (lv[j] == bv && li[j] < bg)) { bv = lv[j]; bg = li[j]; bj = j; }
            int bcode = (lane << 4) | bj;
#pragma unroll
            for (int off = 1; off < 64; off <<= 1) {
                float ov = __shfl_xor(bv, off);
                int   og = __shfl_xor(bg, off);
                int   oc = __shfl_xor(bcode, off);
                if (ov > bv || (ov == bv && og < bg)) { bv = ov; bg = og; bcode = oc; }
            }
            if ((bcode >> 4) == lane) {
                int wj = bcode & 15;
#pragma unroll
                for (int j = 0; j < 16; ++j) if (j == wj) lv[j] = -__builtin_inff();
            }
            if (lane == 0) { selw[it] = bv; seli[it] = bg; }
        }
    }
    __syncthreads();

    if (tid < 64) {
        float x = selw[tid];
        float mx = x;
#pragma unroll
        for (int off = 1; off < 64; off <<= 1) mx = fmaxf(mx, __shfl_xor(mx, off));
        float e = expf(x - mx);
        float s = e;
#pragma unroll
        for (int off = 1; off < 64; off <<= 1) s += __shfl_xor(s, off);
        selw[tid] = e / s;
        out[DD + tid] = (float)seli[tid];
    }
    __syncthreads();

    for (int d = tid; d < DD; d += 256) {
        float accv = 0.f;
        for (int i = 0; i < 64; ++i)
            accv += selw[i] * values[(size_t)seli[i] * DD + d];
        out[d] = accv;
    }
}

// ---------------------------------------------------------------------------
extern "C" void kernel_launch(void* const* d_in, const int* in_sizes, int n_in,
                              void* d_out, int out_size, void* d_ws, size_t ws_size,
                              hipStream_t stream) {
    (void)in_sizes; (void)n_in; (void)out_size; (void)ws_size;
    const float* queries = (const float*)d_in[0];
    const float* keys    = (const float*)d_in[1];
    const float* values  = (const float*)d_in[2];
    const float* affine  = (const float*)d_in[3];
    float* out = (float*)d_out;
    char*  ws  = (char*)d_ws;

    unsigned short* qstage = (unsigned short*)(ws + QSTAGE_OFF);
    float* scores = (float*)(ws + SCORES_OFF);
    int*   cidx   = (int*)(ws + CIDX_OFF);
    float* resc   = (float*)(ws + RESC_OFF);
    int*   cnt    = (int*)(ws + CNT_OFF);
    unsigned int* hist = (unsigned int*)(ws + HIST_OFF);
    float* vlo    = (float*)(ws + VLO_OFF);

    hipFuncSetAttribute((const void*)scores_gemm,
                        hipFuncAttributeMaxDynamicSharedMemorySize, GEMM_LDS);

    prep_q<<<(NKS * NQ * 4) / 256, 256, 0, stream>>>(queries, affine, qstage);
    scores_gemm<<<MBLOCKS, 512, GEMM_LDS, stream>>>(keys, qstage, scores);
    zero_hist<<<8, 1024, 0, stream>>>(hist, cnt);
    hist_build<<<200, 256, 0, stream>>>(scores, hist);
    find_thresh<<<1, 1024, 0, stream>>>(hist, vlo);
    collect<<<200, 256, 0, stream>>>(scores, vlo, cidx, cnt);
    rescore<<<CAP, 256, 0, stream>>>(queries, affine, keys, cidx, cnt, resc);
    final_select<<<1, 256, 0, stream>>>(cidx, resc, cnt, values, out);
}

// Round 4
// 758.259 us; speedup vs baseline: 1.0463x; 1.0463x over previous
//
#include <hip/hip_runtime.h>
#include <cstdint>
#include <cstddef>

// ---------------------------------------------------------------------------
// AffineMultiQueryHardAttentionEncoder
//   scores[m] = max_n ( (q[n]*a) . k[m] ), top-64, softmax, sum w_i * V[idx_i]
// R4: GEMM -> A(keys) direct global->reg->bf16(perm)->MFMA (no LDS, no barrier
//     dependency; L1 serves 7/8 waves), B via glds dbuf (L2-resident).
//     hist_build -> per-block LDS histogram (fixes 338us atomic serialization).
// ---------------------------------------------------------------------------

typedef __attribute__((ext_vector_type(8))) short bf16x8;
typedef __attribute__((ext_vector_type(4))) float f32x4;
typedef __attribute__((ext_vector_type(4))) unsigned int u32x4;

static constexpr int NQ = 512;
static constexpr int DD = 1024;
static constexpr int MK = 100000;
static constexpr int BM = 64;
static constexpr int BK = 32;
static constexpr int NKS = DD / BK;                 // 32
static constexpr int MBLOCKS = (MK + BM - 1) / BM;  // 1563
static constexpr int CAP = 1024;

// workspace layout (bytes)
static constexpr size_t QSTAGE_OFF   = 0;                          // [32][512][4][16B] = 1 MiB
static constexpr size_t QSTAGE_BYTES = (size_t)NKS * NQ * 64;
static constexpr size_t SCORES_OFF   = QSTAGE_OFF + QSTAGE_BYTES;
static constexpr size_t SCORES_BYTES = (size_t)MBLOCKS * BM * sizeof(float);
static constexpr size_t CIDX_OFF     = SCORES_OFF + SCORES_BYTES;
static constexpr size_t RESC_OFF     = CIDX_OFF + (size_t)CAP * 4;
static constexpr size_t CNT_OFF      = RESC_OFF + (size_t)CAP * 4;
static constexpr size_t HIST_OFF     = CNT_OFF + 64;
static constexpr size_t VLO_OFF      = HIST_OFF + 8192 * 4;

// LDS: Bbuf[2] 512x64B = 65536 B (A never touches LDS)
static constexpr int GEMM_LDS = 2 * 32768;

static __device__ __forceinline__ unsigned short f32_to_bf16_rne(float f) {
    unsigned int u = __float_as_uint(f);
    unsigned int r = (u + 0x7FFFu + ((u >> 16) & 1u)) >> 16;
    return (unsigned short)r;
}
static __device__ __forceinline__ unsigned int xform(float f) {
    unsigned int u = __float_as_uint(f);
    return u ^ ((unsigned int)((int)u >> 31) | 0x80000000u);
}
static __device__ __forceinline__ float unxform(unsigned int u) {
    unsigned int b = (u & 0x80000000u) ? (u ^ 0x80000000u) : ~u;
    return __uint_as_float(b);
}
static __device__ __forceinline__ int swz4(int row) {   // chunk swizzle within 64B row
    return ((row >> 2) ^ row) & 3;
}
// pack two f32 -> two bf16 (truncate) in ONE v_perm_b32: [bf16(hi) : bf16(lo)]
static __device__ __forceinline__ unsigned int pack_trunc(float hi, float lo) {
    return __builtin_amdgcn_perm(__float_as_uint(hi), __float_as_uint(lo), 0x07060302u);
}

typedef __attribute__((address_space(1))) const unsigned int g1u32;
typedef __attribute__((address_space(3))) unsigned int l3u32;
static __device__ __forceinline__ void async16(const void* g, void* l) {
    __builtin_amdgcn_global_load_lds((g1u32*)g, (l3u32*)(uintptr_t)l, 16, 0, 0);
}

// ---------------------------------------------------------------------------
// prep: qa = q*a -> bf16 (RNE), pre-swizzled: chunk id = (ks*512+row)*4 + c
// holds qa[row][ks*32 + (c ^ swz4(row))*8 .. +7]
// ---------------------------------------------------------------------------
__global__ void prep_q(const float* __restrict__ q, const float* __restrict__ a,
                       unsigned short* __restrict__ qs) {
    int id  = blockIdx.x * 256 + threadIdx.x;   // 0..65535
    int c   = id & 3;
    int row = (id >> 2) & (NQ - 1);
    int ks  = id >> 11;
    int kb  = ks * BK + (c ^ swz4(row)) * 8;

    const float* qrow = q + (size_t)row * DD + kb;
    float4 v0 = *(const float4*)(qrow);
    float4 v1 = *(const float4*)(qrow + 4);
    float4 a0 = *(const float4*)(a + kb);
    float4 a1 = *(const float4*)(a + kb + 4);
    float f[8] = {v0.x * a0.x, v0.y * a0.y, v0.z * a0.z, v0.w * a0.w,
                  v1.x * a1.x, v1.y * a1.y, v1.z * a1.z, v1.w * a1.w};
    bf16x8 o;
#pragma unroll
    for (int j = 0; j < 8; ++j) o[j] = (short)f32_to_bf16_rne(f[j]);
    *(bf16x8*)(qs + (size_t)id * 8) = o;
}

// ---------------------------------------------------------------------------
// prescreen GEMM + column max
//   A: keys f32 direct global->reg, perm-pack to bf16 (L1-shared across waves)
//   B: qstage bf16 via global_load_lds, double-buffered
// ---------------------------------------------------------------------------
__launch_bounds__(512, 4)
__global__ void scores_gemm(const float* __restrict__ keys,
                            const unsigned short* __restrict__ qs,
                            float* __restrict__ scores) {
    extern __shared__ char smem[];
    const int tid  = threadIdx.x;
    const int wid  = tid >> 6;
    const int lane = tid & 63;
    const int g    = lane >> 4;
    const int r16  = lane & 15;
    const int m0   = blockIdx.x * BM;

    // B staging: per-wave 64 rows, linear glds dest; src pre-swizzled
    const char* bsrc = (const char*)qs + (size_t)(wid * 64) * 64 + (size_t)lane * 16;
    const int bdst0 = wid * 4096;   // within a 32768B buffer

    // B fragment read offsets (swizzled)
    int boff[4];
#pragma unroll
    for (int ct = 0; ct < 4; ++ct) {
        int row = wid * 64 + ct * 16 + r16;
        boff[ct] = row * 64 + (((g ^ swz4(row)) & 3) << 4);
    }

    // A pointers: lane (r16,g) reads keys[m0+rt*16+r16][ks*32+g*8 .. +7]
    const float* ak[4];
#pragma unroll
    for (int rt = 0; rt < 4; ++rt) {
        int r = m0 + rt * 16 + r16;
        if (r >= MK) r = MK - 1;           // clamp (output masked later)
        ak[rt] = keys + (size_t)r * DD + g * 8;
    }

    f32x4 acc[4][4] = {};

    // prologue: stage B(0)
#pragma unroll
    for (int j = 0; j < 4; ++j)
        async16(bsrc + j * 1024, smem + bdst0 + j * 1024);
    __syncthreads();

    for (int ks = 0; ks < NKS; ++ks) {
        const int cur = ks & 1, nxt = cur ^ 1;
        if (ks + 1 < NKS) {
#pragma unroll
            for (int j = 0; j < 4; ++j)
                async16(bsrc + (size_t)(ks + 1) * 32768 + j * 1024,
                        smem + nxt * 32768 + bdst0 + j * 1024);
        }
        // B fragments for this K-step
        bf16x8 bh[4];
#pragma unroll
        for (int ct = 0; ct < 4; ++ct)
            bh[ct] = *(const bf16x8*)(smem + cur * 32768 + boff[ct]);

        // A: software-pipelined over rt (load rt+1 while MFMA-ing rt)
        float4 a0 = *(const float4*)(ak[0] + ks * 32);
        float4 a1 = *(const float4*)(ak[0] + ks * 32 + 4);
#pragma unroll
        for (int rt = 0; rt < 4; ++rt) {
            float4 n0 = a0, n1 = a1;
            if (rt < 3) {
                n0 = *(const float4*)(ak[rt + 1] + ks * 32);
                n1 = *(const float4*)(ak[rt + 1] + ks * 32 + 4);
            }
            u32x4 u;
            u.x = pack_trunc(a0.y, a0.x);
            u.y = pack_trunc(a0.w, a0.z);
            u.z = pack_trunc(a1.y, a1.x);
            u.w = pack_trunc(a1.w, a1.z);
            bf16x8 af = __builtin_bit_cast(bf16x8, u);
            __builtin_amdgcn_s_setprio(1);
#pragma unroll
            for (int ct = 0; ct < 4; ++ct)
                acc[rt][ct] = __builtin_amdgcn_mfma_f32_16x16x32_bf16(af, bh[ct], acc[rt][ct], 0, 0, 0);
            __builtin_amdgcn_s_setprio(0);
            a0 = n0; a1 = n1;
        }
        __syncthreads();   // drains B-glds(ks+1) (L2-resident -> cheap)
    }

    // epilogue: per-lane max over ct, shfl-reduce over 16 query-lanes,
    // cross-wave fold via LDS
    float* wmax = (float*)smem;   // [8][64], safe after final barrier
#pragma unroll
    for (int rt = 0; rt < 4; ++rt) {
#pragma unroll
        for (int r = 0; r < 4; ++r) {
            float mx = acc[rt][0][r];
            mx = fmaxf(mx, acc[rt][1][r]);
            mx = fmaxf(mx, acc[rt][2][r]);
            mx = fmaxf(mx, acc[rt][3][r]);
#pragma unroll
            for (int off = 1; off < 16; off <<= 1)
                mx = fmaxf(mx, __shfl_xor(mx, off));
            if (r16 == 0) wmax[wid * 64 + rt * 16 + g * 4 + r] = mx;
        }
    }
    __syncthreads();
    if (tid < BM) {
        float mx = wmax[tid];
#pragma unroll
        for (int w = 1; w < 8; ++w) mx = fmaxf(mx, wmax[w * 64 + tid]);
        int gm = m0 + tid;
        if (gm < MK) scores[gm] = mx;
    }
}

// ---------------------------------------------------------------------------
// threshold select, multi-block
// ---------------------------------------------------------------------------
__global__ void zero_hist(unsigned int* __restrict__ hist, int* __restrict__ cnt) {
    int i = blockIdx.x * 1024 + threadIdx.x;
    if (i < 8192) hist[i] = 0;
    if (i == 0) cnt[0] = 0;
}

// per-block LDS histogram -> merge nonzero bins (avoids global hot-bin serial)
__global__ void hist_build(const float* __restrict__ scores, unsigned int* __restrict__ hist) {
    __shared__ unsigned int lh[8192];
    for (int i = threadIdx.x; i < 8192; i += 256) lh[i] = 0;
    __syncthreads();
    for (int i = blockIdx.x * 256 + threadIdx.x; i < MK; i += gridDim.x * 256)
        atomicAdd(&lh[xform(scores[i]) >> 19], 1u);
    __syncthreads();
    for (int i = threadIdx.x; i < 8192; i += 256) {
        unsigned int c = lh[i];
        if (c) atomicAdd(&hist[i], c);
    }
}

__launch_bounds__(1024)
__global__ void find_thresh(const unsigned int* __restrict__ hist, float* __restrict__ vlo) {
    __shared__ unsigned int s0[1024], s1[1024];
    const int tid = threadIdx.x;
    unsigned int s = 0;
#pragma unroll
    for (int j = 0; j < 8; ++j) s += hist[tid * 8 + j];
    s0[tid] = s;
    __syncthreads();
    unsigned int* src = s0;
    unsigned int* dst = s1;
    for (int off = 1; off < 1024; off <<= 1) {
        unsigned int v = src[tid] + ((tid + off < 1024) ? src[tid + off] : 0u);
        __syncthreads();
        dst[tid] = v;
        __syncthreads();
        unsigned int* t = src; src = dst; dst = t;
    }
    unsigned int suf  = src[tid];
    unsigned int sufn = (tid < 1023) ? src[tid + 1] : 0u;
    if (suf >= 64u && sufn < 64u) {
        unsigned int acc = sufn;
        int b = tid * 8 + 7;
        for (;; --b) { acc += hist[b]; if (acc >= 64u) break; }
        vlo[0] = unxform(((unsigned int)b) << 19) - 1.0f;   // margin 1.0
    }
}

__global__ void collect(const float* __restrict__ scores, const float* __restrict__ vlo,
                        int* __restrict__ cidx, int* __restrict__ cnt) {
    const float t = vlo[0];
    for (int i = blockIdx.x * 256 + threadIdx.x; i < MK; i += gridDim.x * 256) {
        if (scores[i] >= t) {
            int p = atomicAdd(cnt, 1);
            if (p < CAP) cidx[p] = i;
        }
    }
}

// ---------------------------------------------------------------------------
// exact f32 rescore: one block per candidate, max over 512 queries
// ---------------------------------------------------------------------------
__launch_bounds__(256)
__global__ void rescore(const float* __restrict__ q, const float* __restrict__ a,
                        const float* __restrict__ keys,
                        const int* __restrict__ cidx, const int* __restrict__ cnt,
                        float* __restrict__ resc) {
    __shared__ float w[1024];
    __shared__ float smax[4];
    const int b = blockIdx.x;
    if (b >= cnt[0]) return;
    const int m   = cidx[b];
    const int tid = threadIdx.x;

    for (int d = tid; d < 1024; d += 256) w[d] = a[d] * keys[(size_t)m * DD + d];
    __syncthreads();

    const int wid = tid >> 6, lane = tid & 63;
    float best = -__builtin_inff();
    for (int n = wid; n < NQ; n += 4) {
        const float* qr = q + (size_t)n * DD;
        float p = 0.f;
#pragma unroll
        for (int j = 0; j < 4; ++j) {
            float4 v  = *(const float4*)(qr + lane * 4 + 256 * j);
            float4 ww = *(const float4*)(&w[lane * 4 + 256 * j]);
            p += v.x * ww.x + v.y * ww.y + v.z * ww.z + v.w * ww.w;
        }
#pragma unroll
        for (int off = 1; off < 64; off <<= 1) p += __shfl_xor(p, off);
        best = fmaxf(best, p);
    }
    if (lane == 0) smax[wid] = best;
    __syncthreads();
    if (tid == 0)
        resc[b] = fmaxf(fmaxf(smax[0], smax[1]), fmaxf(smax[2], smax[3]));
}

// ---------------------------------------------------------------------------
// final: top-64 over candidates (exact vals, tie: idx asc), softmax, gather V
// ---------------------------------------------------------------------------
__launch_bounds__(256)
__global__ void final_select(const int* __restrict__ cidx, const float* __restrict__ resc,
                             const int* __restrict__ cnt, const float* __restrict__ values,
                             float* __restrict__ out) {
    __shared__ float selw[64];
    __shared__ int   seli[64];
    const int tid = threadIdx.x;
    int nc = cnt[0];
    if (nc > CAP) nc = CAP;

    if (tid < 64) {
        const int lane = tid;
        float lv[16]; int li[16];
#pragma unroll
        for (int j = 0; j < 16; ++j) {
            int slot = lane + 64 * j;
            bool ok = slot < nc;
            lv[j] = ok ? resc[slot] : -__builtin_inff();
            li[j] = ok ? cidx[slot] : 0x7fffffff;
        }
        for (int it = 0; it < 64; ++it) {
            float bv = -__builtin_inff();
            int bg = 0x7fffffff, bj = 0;
#pragma unroll
            for (int j = 0; j < 16; ++j)
                if (lv[j] > bv || (lv[j] == bv && li[j] < bg)) { bv = lv[j]; bg = li[j]; bj = j; }
            int bcode = (lane << 4) | bj;
#pragma unroll
            for (int off = 1; off < 64; off <<= 1) {
                float ov = __shfl_xor(bv, off);
                int   og = __shfl_xor(bg, off);
                int   oc = __shfl_xor(bcode, off);
                if (ov > bv || (ov == bv && og < bg)) { bv = ov; bg = og; bcode = oc; }
            }
            if ((bcode >> 4) == lane) {
                int wj = bcode & 15;
#pragma unroll
                for (int j = 0; j < 16; ++j) if (j == wj) lv[j] = -__builtin_inff();
            }
            if (lane == 0) { selw[it] = bv; seli[it] = bg; }
        }
    }
    __syncthreads();

    if (tid < 64) {
        float x = selw[tid];
        float mx = x;
#pragma unroll
        for (int off = 1; off < 64; off <<= 1) mx = fmaxf(mx, __shfl_xor(mx, off));
        float e = expf(x - mx);
        float s = e;
#pragma unroll
        for (int off = 1; off < 64; off <<= 1) s += __shfl_xor(s, off);
        selw[tid] = e / s;
        out[DD + tid] = (float)seli[tid];
    }
    __syncthreads();

    for (int d = tid; d < DD; d += 256) {
        float accv = 0.f;
        for (int i = 0; i < 64; ++i)
            accv += selw[i] * values[(size_t)seli[i] * DD + d];
        out[d] = accv;
    }
}

// ---------------------------------------------------------------------------
extern "C" void kernel_launch(void* const* d_in, const int* in_sizes, int n_in,
                              void* d_out, int out_size, void* d_ws, size_t ws_size,
                              hipStream_t stream) {
    (void)in_sizes; (void)n_in; (void)out_size; (void)ws_size;
    const float* queries = (const float*)d_in[0];
    const float* keys    = (const float*)d_in[1];
    const float* values  = (const float*)d_in[2];
    const float* affine  = (const float*)d_in[3];
    float* out = (float*)d_out;
    char*  ws  = (char*)d_ws;

    unsigned short* qstage = (unsigned short*)(ws + QSTAGE_OFF);
    float* scores = (float*)(ws + SCORES_OFF);
    int*   cidx   = (int*)(ws + CIDX_OFF);
    float* resc   = (float*)(ws + RESC_OFF);
    int*   cnt    = (int*)(ws + CNT_OFF);
    unsigned int* hist = (unsigned int*)(ws + HIST_OFF);
    float* vlo    = (float*)(ws + VLO_OFF);

    hipFuncSetAttribute((const void*)scores_gemm,
                        hipFuncAttributeMaxDynamicSharedMemorySize, GEMM_LDS);

    prep_q<<<(NKS * NQ * 4) / 256, 256, 0, stream>>>(queries, affine, qstage);
    scores_gemm<<<MBLOCKS, 512, GEMM_LDS, stream>>>(keys, qstage, scores);
    zero_hist<<<8, 1024, 0, stream>>>(hist, cnt);
    hist_build<<<64, 256, 0, stream>>>(scores, hist);
    find_thresh<<<1, 1024, 0, stream>>>(hist, vlo);
    collect<<<200, 256, 0, stream>>>(scores, vlo, cidx, cnt);
    rescore<<<CAP, 256, 0, stream>>>(queries, affine, keys, cidx, cnt, resc);
    final_select<<<1, 256, 0, stream>>>(cidx, resc, cnt, values, out);
}

// Round 5
// 534.545 us; speedup vs baseline: 1.4842x; 1.4185x over previous
//
#include <hip/hip_runtime.h>
#include <cstdint>
#include <cstddef>

// ---------------------------------------------------------------------------
// AffineMultiQueryHardAttentionEncoder
//   scores[m] = max_n ( (q[n]*a) . k[m] ), top-64, softmax, sum w_i * V[idx_i]
// R5: ALL gemm HBM streams made sequential.
//   - prep_keys: keys f32 (coalesced read) -> kstage bf16 tiled+swizzled
//     [mb][ks][row][128B] (coalesced write).  Fixes the 550 GB/s scatter
//     ceiling that dominated R1-R4 (64 rows x 256B stripes @ 4KB stride).
//   - scores_gemm: pure bf16 m97-style 2-barrier loop; A and B both staged
//     via global_load_lds from pre-swizzled buffers. 72KB LDS -> 2 blocks/CU.
//   - select: multi-block hist (R4) + exact f32 rescore + final.
// ---------------------------------------------------------------------------

typedef __attribute__((ext_vector_type(8))) short bf16x8;
typedef __attribute__((ext_vector_type(4))) float f32x4;

static constexpr int NQ = 512;
static constexpr int DD = 1024;
static constexpr int MK = 100000;
static constexpr int BM = 64;
static constexpr int BK = 64;
static constexpr int NKS = DD / BK;                 // 16
static constexpr int MBLOCKS = (MK + BM - 1) / BM;  // 1563
static constexpr int CAP = 1024;

// workspace layout (bytes)
static constexpr size_t KSTAGE_OFF   = 0;   // [1563][16][64][128B] = 204,865,536
static constexpr size_t KSTAGE_BYTES = (size_t)MBLOCKS * NKS * BM * 128;
static constexpr size_t QSTAGE_OFF   = KSTAGE_OFF + KSTAGE_BYTES;   // [16][512][128B] = 1 MiB
static constexpr size_t QSTAGE_BYTES = (size_t)NKS * NQ * 128;
static constexpr size_t SCORES_OFF   = QSTAGE_OFF + QSTAGE_BYTES;
static constexpr size_t SCORES_BYTES = (size_t)MBLOCKS * BM * sizeof(float);
static constexpr size_t CIDX_OFF     = SCORES_OFF + SCORES_BYTES;
static constexpr size_t RESC_OFF     = CIDX_OFF + (size_t)CAP * 4;
static constexpr size_t CNT_OFF      = RESC_OFF + (size_t)CAP * 4;
static constexpr size_t HIST_OFF     = CNT_OFF + 64;
static constexpr size_t VLO_OFF      = HIST_OFF + 8192 * 4;

// LDS: A [64][128B] = 8KB, B [512][128B] = 64KB -> 73728 B -> 2 blocks/CU
static constexpr int AOFF = 0;
static constexpr int BOFF = 8192;
static constexpr int GEMM_LDS = 8192 + 65536;

static __device__ __forceinline__ unsigned short f32_to_bf16_rne(float f) {
    unsigned int u = __float_as_uint(f);
    unsigned int r = (u + 0x7FFFu + ((u >> 16) & 1u)) >> 16;
    return (unsigned short)r;
}
static __device__ __forceinline__ unsigned int xform(float f) {
    unsigned int u = __float_as_uint(f);
    return u ^ ((unsigned int)((int)u >> 31) | 0x80000000u);
}
static __device__ __forceinline__ float unxform(unsigned int u) {
    unsigned int b = (u & 0x80000000u) ? (u ^ 0x80000000u) : ~u;
    return __uint_as_float(b);
}

typedef __attribute__((address_space(1))) const unsigned int g1u32;
typedef __attribute__((address_space(3))) unsigned int l3u32;
static __device__ __forceinline__ void async16(const void* g, void* l) {
    __builtin_amdgcn_global_load_lds((g1u32*)g, (l3u32*)(uintptr_t)l, 16, 0, 0);
}

// ---------------------------------------------------------------------------
// prep_q: qa = q*a -> bf16 RNE, pre-swizzled: chunk id = (ks*512+row)*8 + p
// holds qa[row][ks*64 + (p^(row&7))*8 .. +7]
// ---------------------------------------------------------------------------
__global__ void prep_q(const float* __restrict__ q, const float* __restrict__ a,
                       unsigned short* __restrict__ qs) {
    int id  = blockIdx.x * 256 + threadIdx.x;   // 0..65535
    int p   = id & 7;
    int row = (id >> 3) & (NQ - 1);
    int ks  = id >> 12;
    int c   = p ^ (row & 7);
    int kb  = ks * BK + c * 8;

    const float* qrow = q + (size_t)row * DD + kb;
    float4 v0 = *(const float4*)(qrow);
    float4 v1 = *(const float4*)(qrow + 4);
    float4 a0 = *(const float4*)(a + kb);
    float4 a1 = *(const float4*)(a + kb + 4);
    float f[8] = {v0.x * a0.x, v0.y * a0.y, v0.z * a0.z, v0.w * a0.w,
                  v1.x * a1.x, v1.y * a1.y, v1.z * a1.z, v1.w * a1.w};
    bf16x8 o;
#pragma unroll
    for (int j = 0; j < 8; ++j) o[j] = (short)f32_to_bf16_rne(f[j]);
    *(bf16x8*)(qs + (size_t)id * 8) = o;
}

// ---------------------------------------------------------------------------
// prep_keys: keys f32 -> kstage bf16, tiled+swizzled:
//   chunk id = ((mb*16+ks)*64 + row)*8 + p holds
//   keys[mb*64+row][ks*64 + (p^(row&7))*8 .. +7]   (0 for padded rows)
// reads coalesced (8 threads cover each 256B window), writes sequential.
// ---------------------------------------------------------------------------
__global__ void prep_keys(const float* __restrict__ keys,
                          unsigned short* __restrict__ kst) {
    size_t id = (size_t)blockIdx.x * 256 + threadIdx.x;   // < 12,804,096
    int p   = (int)(id & 7);
    int row = (int)((id >> 3) & 63);
    int ks  = (int)((id >> 9) & 15);
    int mb  = (int)(id >> 13);
    int gm  = mb * 64 + row;
    bf16x8 o;
    if (gm < MK) {
        int col = ks * BK + (p ^ (row & 7)) * 8;
        const float* src = keys + (size_t)gm * DD + col;
        float4 v0 = *(const float4*)(src);
        float4 v1 = *(const float4*)(src + 4);
        float f[8] = {v0.x, v0.y, v0.z, v0.w, v1.x, v1.y, v1.z, v1.w};
#pragma unroll
        for (int j = 0; j < 8; ++j) o[j] = (short)f32_to_bf16_rne(f[j]);
    } else {
#pragma unroll
        for (int j = 0; j < 8; ++j) o[j] = 0;
    }
    *(bf16x8*)(kst + id * 8) = o;
}

// ---------------------------------------------------------------------------
// prescreen GEMM + column max: pure bf16, A+B via global_load_lds
// ---------------------------------------------------------------------------
__launch_bounds__(512, 4)
__global__ void scores_gemm(const unsigned short* __restrict__ kstage,
                            const unsigned short* __restrict__ qs,
                            float* __restrict__ scores) {
    extern __shared__ char smem[];
    const int tid  = threadIdx.x;
    const int wid  = tid >> 6;
    const int lane = tid & 63;
    const int g    = lane >> 4;
    const int r16  = lane & 15;

    // bijective XCD swizzle (m204): nwg = 1563, q=195, r=3
    const int nwg = gridDim.x;
    const int qq  = nwg >> 3, rr = nwg & 7;
    const int xcd = blockIdx.x & 7, loc = blockIdx.x >> 3;
    const int mb  = (xcd < rr ? xcd * (qq + 1) : rr * (qq + 1) + (xcd - rr) * qq) + loc;
    const int m0  = mb * BM;

    // staging sources (pre-swizzled, linear in the order glds writes)
    const char* asrc = (const char*)kstage + ((size_t)mb * NKS) * 8192
                     + wid * 1024 + lane * 16;
    const char* bsrc = (const char*)qs + (size_t)(wid * 64) * 128 + (size_t)lane * 16;

    // fragment read offsets
    int aoff[2][4], boff[2][4];
#pragma unroll
    for (int s = 0; s < 2; ++s) {
#pragma unroll
        for (int rt = 0; rt < 4; ++rt) {
            int row = rt * 16 + r16;
            aoff[s][rt] = AOFF + row * 128 + (((s * 4 + g) ^ (row & 7)) << 4);
        }
#pragma unroll
        for (int ct = 0; ct < 4; ++ct) {
            int row = wid * 64 + ct * 16 + r16;
            boff[s][ct] = BOFF + row * 128 + (((s * 4 + g) ^ (row & 7)) << 4);
        }
    }

    f32x4 acc[4][4] = {};

    for (int ks = 0; ks < NKS; ++ks) {
        // stage A (1 glds/wave) + B (8 glds/wave), all linear dest
        async16(asrc + (size_t)ks * 8192, smem + AOFF + wid * 1024);
#pragma unroll
        for (int i = 0; i < 8; ++i)
            async16(bsrc + (size_t)ks * 65536 + i * 1024,
                    smem + BOFF + wid * 8192 + i * 1024);
        __syncthreads();

#pragma unroll
        for (int s = 0; s < 2; ++s) {
            bf16x8 ah[4], bh[4];
#pragma unroll
            for (int rt = 0; rt < 4; ++rt) ah[rt] = *(const bf16x8*)(smem + aoff[s][rt]);
#pragma unroll
            for (int ct = 0; ct < 4; ++ct) bh[ct] = *(const bf16x8*)(smem + boff[s][ct]);
#pragma unroll
            for (int rt = 0; rt < 4; ++rt)
#pragma unroll
                for (int ct = 0; ct < 4; ++ct)
                    acc[rt][ct] = __builtin_amdgcn_mfma_f32_16x16x32_bf16(ah[rt], bh[ct], acc[rt][ct], 0, 0, 0);
        }
        __syncthreads();
    }

    // epilogue: per-lane max over ct, shfl over the 16 query-cols, cross-wave
    float* wmax = (float*)smem;   // [8][64], safe after final barrier
#pragma unroll
    for (int rt = 0; rt < 4; ++rt) {
#pragma unroll
        for (int r = 0; r < 4; ++r) {
            float mx = acc[rt][0][r];
            mx = fmaxf(mx, acc[rt][1][r]);
            mx = fmaxf(mx, acc[rt][2][r]);
            mx = fmaxf(mx, acc[rt][3][r]);
#pragma unroll
            for (int off = 1; off < 16; off <<= 1)
                mx = fmaxf(mx, __shfl_xor(mx, off));
            if (r16 == 0) wmax[wid * 64 + rt * 16 + g * 4 + r] = mx;
        }
    }
    __syncthreads();
    if (tid < BM) {
        float mx = wmax[tid];
#pragma unroll
        for (int w = 1; w < 8; ++w) mx = fmaxf(mx, wmax[w * 64 + tid]);
        int gm = m0 + tid;
        if (gm < MK) scores[gm] = mx;
    }
}

// ---------------------------------------------------------------------------
// threshold select, multi-block
// ---------------------------------------------------------------------------
__global__ void zero_hist(unsigned int* __restrict__ hist, int* __restrict__ cnt) {
    int i = blockIdx.x * 1024 + threadIdx.x;
    if (i < 8192) hist[i] = 0;
    if (i == 0) cnt[0] = 0;
}

__global__ void hist_build(const float* __restrict__ scores, unsigned int* __restrict__ hist) {
    __shared__ unsigned int lh[8192];
    for (int i = threadIdx.x; i < 8192; i += 256) lh[i] = 0;
    __syncthreads();
    for (int i = blockIdx.x * 256 + threadIdx.x; i < MK; i += gridDim.x * 256)
        atomicAdd(&lh[xform(scores[i]) >> 19], 1u);
    __syncthreads();
    for (int i = threadIdx.x; i < 8192; i += 256) {
        unsigned int c = lh[i];
        if (c) atomicAdd(&hist[i], c);
    }
}

__launch_bounds__(1024)
__global__ void find_thresh(const unsigned int* __restrict__ hist, float* __restrict__ vlo) {
    __shared__ unsigned int s0[1024], s1[1024];
    const int tid = threadIdx.x;
    unsigned int s = 0;
#pragma unroll
    for (int j = 0; j < 8; ++j) s += hist[tid * 8 + j];
    s0[tid] = s;
    __syncthreads();
    unsigned int* src = s0;
    unsigned int* dst = s1;
    for (int off = 1; off < 1024; off <<= 1) {
        unsigned int v = src[tid] + ((tid + off < 1024) ? src[tid + off] : 0u);
        __syncthreads();
        dst[tid] = v;
        __syncthreads();
        unsigned int* t = src; src = dst; dst = t;
    }
    unsigned int suf  = src[tid];
    unsigned int sufn = (tid < 1023) ? src[tid + 1] : 0u;
    if (suf >= 64u && sufn < 64u) {
        unsigned int acc = sufn;
        int b = tid * 8 + 7;
        for (;; --b) { acc += hist[b]; if (acc >= 64u) break; }
        vlo[0] = unxform(((unsigned int)b) << 19) - 1.0f;   // margin 1.0
    }
}

__global__ void collect(const float* __restrict__ scores, const float* __restrict__ vlo,
                        int* __restrict__ cidx, int* __restrict__ cnt) {
    const float t = vlo[0];
    for (int i = blockIdx.x * 256 + threadIdx.x; i < MK; i += gridDim.x * 256) {
        if (scores[i] >= t) {
            int p = atomicAdd(cnt, 1);
            if (p < CAP) cidx[p] = i;
        }
    }
}

// ---------------------------------------------------------------------------
// exact f32 rescore: one block per candidate, max over 512 queries
// ---------------------------------------------------------------------------
__launch_bounds__(256)
__global__ void rescore(const float* __restrict__ q, const float* __restrict__ a,
                        const float* __restrict__ keys,
                        const int* __restrict__ cidx, const int* __restrict__ cnt,
                        float* __restrict__ resc) {
    __shared__ float w[1024];
    __shared__ float smax[4];
    const int b = blockIdx.x;
    if (b >= cnt[0]) return;
    const int m   = cidx[b];
    const int tid = threadIdx.x;

    for (int d = tid; d < 1024; d += 256) w[d] = a[d] * keys[(size_t)m * DD + d];
    __syncthreads();

    const int wid = tid >> 6, lane = tid & 63;
    float best = -__builtin_inff();
    for (int n = wid; n < NQ; n += 4) {
        const float* qr = q + (size_t)n * DD;
        float p = 0.f;
#pragma unroll
        for (int j = 0; j < 4; ++j) {
            float4 v  = *(const float4*)(qr + lane * 4 + 256 * j);
            float4 ww = *(const float4*)(&w[lane * 4 + 256 * j]);
            p += v.x * ww.x + v.y * ww.y + v.z * ww.z + v.w * ww.w;
        }
#pragma unroll
        for (int off = 1; off < 64; off <<= 1) p += __shfl_xor(p, off);
        best = fmaxf(best, p);
    }
    if (lane == 0) smax[wid] = best;
    __syncthreads();
    if (tid == 0)
        resc[b] = fmaxf(fmaxf(smax[0], smax[1]), fmaxf(smax[2], smax[3]));
}

// ---------------------------------------------------------------------------
// final: top-64 over candidates (exact vals, tie: idx asc), softmax, gather V
// ---------------------------------------------------------------------------
__launch_bounds__(256)
__global__ void final_select(const int* __restrict__ cidx, const float* __restrict__ resc,
                             const int* __restrict__ cnt, const float* __restrict__ values,
                             float* __restrict__ out) {
    __shared__ float selw[64];
    __shared__ int   seli[64];
    const int tid = threadIdx.x;
    int nc = cnt[0];
    if (nc > CAP) nc = CAP;

    if (tid < 64) {
        const int lane = tid;
        float lv[16]; int li[16];
#pragma unroll
        for (int j = 0; j < 16; ++j) {
            int slot = lane + 64 * j;
            bool ok = slot < nc;
            lv[j] = ok ? resc[slot] : -__builtin_inff();
            li[j] = ok ? cidx[slot] : 0x7fffffff;
        }
        for (int it = 0; it < 64; ++it) {
            float bv = -__builtin_inff();
            int bg = 0x7fffffff, bj = 0;
#pragma unroll
            for (int j = 0; j < 16; ++j)
                if (lv[j] > bv || (lv[j] == bv && li[j] < bg)) { bv = lv[j]; bg = li[j]; bj = j; }
            int bcode = (lane << 4) | bj;
#pragma unroll
            for (int off = 1; off < 64; off <<= 1) {
                float ov = __shfl_xor(bv, off);
                int   og = __shfl_xor(bg, off);
                int   oc = __shfl_xor(bcode, off);
                if (ov > bv || (ov == bv && og < bg)) { bv = ov; bg = og; bcode = oc; }
            }
            if ((bcode >> 4) == lane) {
                int wj = bcode & 15;
#pragma unroll
                for (int j = 0; j < 16; ++j) if (j == wj) lv[j] = -__builtin_inff();
            }
            if (lane == 0) { selw[it] = bv; seli[it] = bg; }
        }
    }
    __syncthreads();

    if (tid < 64) {
        float x = selw[tid];
        float mx = x;
#pragma unroll
        for (int off = 1; off < 64; off <<= 1) mx = fmaxf(mx, __shfl_xor(mx, off));
        float e = expf(x - mx);
        float s = e;
#pragma unroll
        for (int off = 1; off < 64; off <<= 1) s += __shfl_xor(s, off);
        selw[tid] = e / s;
        out[DD + tid] = (float)seli[tid];
    }
    __syncthreads();

    for (int d = tid; d < DD; d += 256) {
        float accv = 0.f;
        for (int i = 0; i < 64; ++i)
            accv += selw[i] * values[(size_t)seli[i] * DD + d];
        out[d] = accv;
    }
}

// ---------------------------------------------------------------------------
extern "C" void kernel_launch(void* const* d_in, const int* in_sizes, int n_in,
                              void* d_out, int out_size, void* d_ws, size_t ws_size,
                              hipStream_t stream) {
    (void)in_sizes; (void)n_in; (void)out_size; (void)ws_size;
    const float* queries = (const float*)d_in[0];
    const float* keys    = (const float*)d_in[1];
    const float* values  = (const float*)d_in[2];
    const float* affine  = (const float*)d_in[3];
    float* out = (float*)d_out;
    char*  ws  = (char*)d_ws;

    unsigned short* kstage = (unsigned short*)(ws + KSTAGE_OFF);
    unsigned short* qstage = (unsigned short*)(ws + QSTAGE_OFF);
    float* scores = (float*)(ws + SCORES_OFF);
    int*   cidx   = (int*)(ws + CIDX_OFF);
    float* resc   = (float*)(ws + RESC_OFF);
    int*   cnt    = (int*)(ws + CNT_OFF);
    unsigned int* hist = (unsigned int*)(ws + HIST_OFF);
    float* vlo    = (float*)(ws + VLO_OFF);

    hipFuncSetAttribute((const void*)scores_gemm,
                        hipFuncAttributeMaxDynamicSharedMemorySize, GEMM_LDS);

    prep_q<<<(NKS * NQ * 8) / 256, 256, 0, stream>>>(queries, affine, qstage);
    prep_keys<<<(MBLOCKS * NKS * BM * 8) / 256, 256, 0, stream>>>(keys, kstage);
    scores_gemm<<<MBLOCKS, 512, GEMM_LDS, stream>>>(kstage, qstage, scores);
    zero_hist<<<8, 1024, 0, stream>>>(hist, cnt);
    hist_build<<<64, 256, 0, stream>>>(scores, hist);
    find_thresh<<<1, 1024, 0, stream>>>(hist, vlo);
    collect<<<200, 256, 0, stream>>>(scores, vlo, cidx, cnt);
    rescore<<<CAP, 256, 0, stream>>>(queries, affine, keys, cidx, cnt, resc);
    final_select<<<1, 256, 0, stream>>>(cidx, resc, cnt, values, out);
}

// Round 6
// 514.805 us; speedup vs baseline: 1.5412x; 1.0383x over previous
//
#include <hip/hip_runtime.h>
#include <cstdint>
#include <cstddef>

// ---------------------------------------------------------------------------
// AffineMultiQueryHardAttentionEncoder
//   scores[m] = max_n ( (q[n]*a) . k[m] ), top-64, softmax, sum w_i * V[idx_i]
// R6: keys read ONCE, in 2KB contiguous bursts, inside the gemm.
//   - no prep_keys pass (R5 paid 820MB, half scattered; R6 pays 410MB clean)
//   - A: global->reg (16x dwordx4 = 1KB bursts) -> bf16 -> swizzled LDS,
//     register prefetch issued a half-pass (~6000cy) ahead of use: HBM stream
//     never stalls on __syncthreads.
//   - B: qstage bf16 kk-granular [32][512][64B], global_load_lds dbuf (L2).
//   - select: hist threshold + exact f32 rescore + final (unchanged).
// ---------------------------------------------------------------------------

typedef __attribute__((ext_vector_type(8))) short bf16x8;
typedef __attribute__((ext_vector_type(4))) float f32x4;

static constexpr int NQ = 512;
static constexpr int DD = 1024;
static constexpr int MK = 100000;
static constexpr int BM = 64;
static constexpr int NKK = DD / 32;                 // 32 mfma K-steps
static constexpr int MBLOCKS = (MK + BM - 1) / BM;  // 1563
static constexpr int CAP = 1024;

// workspace layout (bytes)
static constexpr size_t QSTAGE_OFF   = 0;                       // [32][512][64B] = 1 MiB
static constexpr size_t QSTAGE_BYTES = (size_t)NKK * NQ * 64;
static constexpr size_t SCORES_OFF   = QSTAGE_OFF + QSTAGE_BYTES;
static constexpr size_t SCORES_BYTES = (size_t)MBLOCKS * BM * sizeof(float);
static constexpr size_t CIDX_OFF     = SCORES_OFF + SCORES_BYTES;
static constexpr size_t RESC_OFF     = CIDX_OFF + (size_t)CAP * 4;
static constexpr size_t CNT_OFF      = RESC_OFF + (size_t)CAP * 4;
static constexpr size_t HIST_OFF     = CNT_OFF + 64;
static constexpr size_t VLO_OFF      = HIST_OFF + 8192 * 4;

// LDS: A [16 kk][64 rows][64B] = 64KB @0 ; B dbuf 2 x [512][64B]=32KB @65536
static constexpr int AOFF = 0;
static constexpr int BOFF = 65536;
static constexpr int GEMM_LDS = 65536 + 2 * 32768;   // 131072 -> 1 block/CU

static __device__ __forceinline__ unsigned short f32_to_bf16_rne(float f) {
    unsigned int u = __float_as_uint(f);
    unsigned int r = (u + 0x7FFFu + ((u >> 16) & 1u)) >> 16;
    return (unsigned short)r;
}
static __device__ __forceinline__ unsigned int xform(float f) {
    unsigned int u = __float_as_uint(f);
    return u ^ ((unsigned int)((int)u >> 31) | 0x80000000u);
}
static __device__ __forceinline__ float unxform(unsigned int u) {
    unsigned int b = (u & 0x80000000u) ? (u ^ 0x80000000u) : ~u;
    return __uint_as_float(b);
}
static __device__ __forceinline__ unsigned long long pack4_bf16(float4 v) {
    unsigned long long u0 = (unsigned long long)(f32_to_bf16_rne(v.x) | ((unsigned int)f32_to_bf16_rne(v.y) << 16));
    unsigned long long u1 = (unsigned long long)(f32_to_bf16_rne(v.z) | ((unsigned int)f32_to_bf16_rne(v.w) << 16));
    return u0 | (u1 << 32);
}

typedef __attribute__((address_space(1))) const unsigned int g1u32;
typedef __attribute__((address_space(3))) unsigned int l3u32;
static __device__ __forceinline__ void async16(const void* g, void* l) {
    __builtin_amdgcn_global_load_lds((g1u32*)g, (l3u32*)(uintptr_t)l, 16, 0, 0);
}

// ---------------------------------------------------------------------------
// prep_q: qa = q*a -> bf16 RNE, kk-granular pre-swizzled:
// chunk id = (kk*512 + row)*4 + c holds qa[row][kk*32 + (c^(row&3))*8 .. +7]
// ---------------------------------------------------------------------------
__global__ void prep_q(const float* __restrict__ q, const float* __restrict__ a,
                       unsigned short* __restrict__ qs) {
    int id  = blockIdx.x * 256 + threadIdx.x;   // 0..65535
    int c   = id & 3;
    int row = (id >> 2) & (NQ - 1);
    int kk  = id >> 11;
    int kb  = kk * 32 + ((c ^ (row & 3)) << 3);

    const float* qrow = q + (size_t)row * DD + kb;
    float4 v0 = *(const float4*)(qrow);
    float4 v1 = *(const float4*)(qrow + 4);
    float4 a0 = *(const float4*)(a + kb);
    float4 a1 = *(const float4*)(a + kb + 4);
    float f[8] = {v0.x * a0.x, v0.y * a0.y, v0.z * a0.z, v0.w * a0.w,
                  v1.x * a1.x, v1.y * a1.y, v1.z * a1.z, v1.w * a1.w};
    bf16x8 o;
#pragma unroll
    for (int j = 0; j < 8; ++j) o[j] = (short)f32_to_bf16_rne(f[j]);
    *(bf16x8*)(qs + (size_t)id * 8) = o;
}

// ---------------------------------------------------------------------------
// prescreen GEMM + column max (keys streamed in 2KB bursts through registers)
// ---------------------------------------------------------------------------
__launch_bounds__(512, 2)
__global__ void scores_gemm(const float* __restrict__ keys,
                            const unsigned short* __restrict__ qs,
                            float* __restrict__ scores) {
    extern __shared__ char smem[];
    const int tid  = threadIdx.x;
    const int wid  = tid >> 6;
    const int lane = tid & 63;
    const int g    = lane >> 4;
    const int r16  = lane & 15;

    // bijective XCD swizzle (m204)
    const int nwg = gridDim.x;
    const int qq  = nwg >> 3, rr = nwg & 7;
    const int xcd = blockIdx.x & 7, loc = blockIdx.x >> 3;
    const int mb  = (xcd < rr ? xcd * (qq + 1) : rr * (qq + 1) + (xcd - rr) * qq) + loc;
    const int m0  = mb * BM;

    // ---- A staging geometry: wave w owns local rows [w*8, w*8+8)
    // load instr (r, h2): lane reads 16B at cols [hp*512 + h2*256 + 4*lane)
    const float* abase[8];
#pragma unroll
    for (int r = 0; r < 8; ++r) {
        int gr = m0 + wid * 8 + r;
        if (gr >= MK) gr = MK - 1;      // clamp; output masked later
        abase[r] = keys + (size_t)gr * DD + lane * 4;
    }
    // ds_write address for (r, h2): lane data = cols [h2*256+4l, +4) of row
    // kk_local = h2*8 + (l>>3); c2 = (l>>1)&3; h = l&1
    const int wrow  = wid * 8;          // + r
    const int kkl_l = lane >> 3;        // 0..7   (+ h2*8)
    const int c2_l  = (lane >> 1) & 7 & 3;
    const int h_l   = lane & 1;
    int awbase[8];                      // per r, for h2=0 (add h2*32768)
#pragma unroll
    for (int r = 0; r < 8; ++r) {
        int row = wrow + r;
        awbase[r] = AOFF + kkl_l * 4096 + row * 64 + (((c2_l ^ (row & 3)) & 3) << 4) + h_l * 8;
    }

    // ---- B staging: per kk, wave w stages rows [w*64, +64) = 4 glds
    const char* bsrc = (const char*)qs + (size_t)(wid * 64) * 64 + (size_t)lane * 16;
    const int   bdst = BOFF + wid * 4096;   // + buf*32768 + i*1024

    // fragment read bases (row&3 == r16&3 for all tiles)
    const int sw = ((g ^ (r16 & 3)) << 4);
    int arow_rd[4], brow_rd[4];
#pragma unroll
    for (int rt = 0; rt < 4; ++rt) arow_rd[rt] = AOFF + (rt * 16 + r16) * 64 + sw;
#pragma unroll
    for (int ct = 0; ct < 4; ++ct) brow_rd[ct] = BOFF + (wid * 64 + ct * 16 + r16) * 64 + sw;

    f32x4 acc[4][4] = {};

    // ---- prologue: load A(hp0) regs, stage B(0), write A(hp0)
    float4 ar[8][2];
#pragma unroll
    for (int r = 0; r < 8; ++r) {
        ar[r][0] = *(const float4*)(abase[r]);
        ar[r][1] = *(const float4*)(abase[r] + 256);
    }
#pragma unroll
    for (int i = 0; i < 4; ++i)
        async16(bsrc + i * 1024, smem + bdst + i * 1024);
#pragma unroll
    for (int r = 0; r < 8; ++r) {
        *(unsigned long long*)(smem + awbase[r])         = pack4_bf16(ar[r][0]);
        *(unsigned long long*)(smem + awbase[r] + 32768) = pack4_bf16(ar[r][1]);
    }
    __syncthreads();

    float4 arn[8][2];
    for (int hp = 0; hp < 2; ++hp) {
        if (hp == 0) {
            // issue A(hp1) loads NOW: ~16 kk-steps (~6000cy) ahead of use
#pragma unroll
            for (int r = 0; r < 8; ++r) {
                arn[r][0] = *(const float4*)(abase[r] + 512);
                arn[r][1] = *(const float4*)(abase[r] + 768);
            }
        }
#pragma unroll 1
        for (int kl = 0; kl < 16; ++kl) {
            const int kk = hp * 16 + kl;
            if (kk + 1 < NKK) {
#pragma unroll
                for (int i = 0; i < 4; ++i)
                    async16(bsrc + (size_t)(kk + 1) * 32768 + i * 1024,
                            smem + ((kk + 1) & 1) * 32768 + bdst + i * 1024);
            }
            bf16x8 ah[4], bh[4];
#pragma unroll
            for (int rt = 0; rt < 4; ++rt)
                ah[rt] = *(const bf16x8*)(smem + kl * 4096 + arow_rd[rt]);
#pragma unroll
            for (int ct = 0; ct < 4; ++ct)
                bh[ct] = *(const bf16x8*)(smem + (kk & 1) * 32768 + brow_rd[ct]);
            __builtin_amdgcn_s_setprio(1);
#pragma unroll
            for (int rt = 0; rt < 4; ++rt)
#pragma unroll
                for (int ct = 0; ct < 4; ++ct)
                    acc[rt][ct] = __builtin_amdgcn_mfma_f32_16x16x32_bf16(ah[rt], bh[ct], acc[rt][ct], 0, 0, 0);
            __builtin_amdgcn_s_setprio(0);
            __syncthreads();
        }
        if (hp == 0) {
#pragma unroll
            for (int r = 0; r < 8; ++r) {
                *(unsigned long long*)(smem + awbase[r])         = pack4_bf16(arn[r][0]);
                *(unsigned long long*)(smem + awbase[r] + 32768) = pack4_bf16(arn[r][1]);
            }
            __syncthreads();
        }
    }

    // ---- epilogue: per-lane max over ct, shfl over 16 query-cols, cross-wave
    float* wmax = (float*)smem;   // reuses A region (post-barrier)
#pragma unroll
    for (int rt = 0; rt < 4; ++rt) {
#pragma unroll
        for (int r = 0; r < 4; ++r) {
            float mx = acc[rt][0][r];
            mx = fmaxf(mx, acc[rt][1][r]);
            mx = fmaxf(mx, acc[rt][2][r]);
            mx = fmaxf(mx, acc[rt][3][r]);
#pragma unroll
            for (int off = 1; off < 16; off <<= 1)
                mx = fmaxf(mx, __shfl_xor(mx, off));
            if (r16 == 0) wmax[wid * 64 + rt * 16 + g * 4 + r] = mx;
        }
    }
    __syncthreads();
    if (tid < BM) {
        float mx = wmax[tid];
#pragma unroll
        for (int w = 1; w < 8; ++w) mx = fmaxf(mx, wmax[w * 64 + tid]);
        int gm = m0 + tid;
        if (gm < MK) scores[gm] = mx;
    }
}

// ---------------------------------------------------------------------------
// threshold select, multi-block
// ---------------------------------------------------------------------------
__global__ void zero_hist(unsigned int* __restrict__ hist, int* __restrict__ cnt) {
    int i = blockIdx.x * 1024 + threadIdx.x;
    if (i < 8192) hist[i] = 0;
    if (i == 0) cnt[0] = 0;
}

__global__ void hist_build(const float* __restrict__ scores, unsigned int* __restrict__ hist) {
    __shared__ unsigned int lh[8192];
    for (int i = threadIdx.x; i < 8192; i += 256) lh[i] = 0;
    __syncthreads();
    for (int i = blockIdx.x * 256 + threadIdx.x; i < MK; i += gridDim.x * 256)
        atomicAdd(&lh[xform(scores[i]) >> 19], 1u);
    __syncthreads();
    for (int i = threadIdx.x; i < 8192; i += 256) {
        unsigned int c = lh[i];
        if (c) atomicAdd(&hist[i], c);
    }
}

__launch_bounds__(1024)
__global__ void find_thresh(const unsigned int* __restrict__ hist, float* __restrict__ vlo) {
    __shared__ unsigned int s0[1024], s1[1024];
    const int tid = threadIdx.x;
    unsigned int s = 0;
#pragma unroll
    for (int j = 0; j < 8; ++j) s += hist[tid * 8 + j];
    s0[tid] = s;
    __syncthreads();
    unsigned int* src = s0;
    unsigned int* dst = s1;
    for (int off = 1; off < 1024; off <<= 1) {
        unsigned int v = src[tid] + ((tid + off < 1024) ? src[tid + off] : 0u);
        __syncthreads();
        dst[tid] = v;
        __syncthreads();
        unsigned int* t = src; src = dst; dst = t;
    }
    unsigned int suf  = src[tid];
    unsigned int sufn = (tid < 1023) ? src[tid + 1] : 0u;
    if (suf >= 64u && sufn < 64u) {
        unsigned int acc = sufn;
        int b = tid * 8 + 7;
        for (;; --b) { acc += hist[b]; if (acc >= 64u) break; }
        vlo[0] = unxform(((unsigned int)b) << 19) - 1.0f;   // margin 1.0
    }
}

__global__ void collect(const float* __restrict__ scores, const float* __restrict__ vlo,
                        int* __restrict__ cidx, int* __restrict__ cnt) {
    const float t = vlo[0];
    for (int i = blockIdx.x * 256 + threadIdx.x; i < MK; i += gridDim.x * 256) {
        if (scores[i] >= t) {
            int p = atomicAdd(cnt, 1);
            if (p < CAP) cidx[p] = i;
        }
    }
}

// ---------------------------------------------------------------------------
// exact f32 rescore: one block per candidate, max over 512 queries
// ---------------------------------------------------------------------------
__launch_bounds__(256)
__global__ void rescore(const float* __restrict__ q, const float* __restrict__ a,
                        const float* __restrict__ keys,
                        const int* __restrict__ cidx, const int* __restrict__ cnt,
                        float* __restrict__ resc) {
    __shared__ float w[1024];
    __shared__ float smax[4];
    const int b = blockIdx.x;
    if (b >= cnt[0]) return;
    const int m   = cidx[b];
    const int tid = threadIdx.x;

    for (int d = tid; d < 1024; d += 256) w[d] = a[d] * keys[(size_t)m * DD + d];
    __syncthreads();

    const int wid = tid >> 6, lane = tid & 63;
    float best = -__builtin_inff();
    for (int n = wid; n < NQ; n += 4) {
        const float* qr = q + (size_t)n * DD;
        float p = 0.f;
#pragma unroll
        for (int j = 0; j < 4; ++j) {
            float4 v  = *(const float4*)(qr + lane * 4 + 256 * j);
            float4 ww = *(const float4*)(&w[lane * 4 + 256 * j]);
            p += v.x * ww.x + v.y * ww.y + v.z * ww.z + v.w * ww.w;
        }
#pragma unroll
        for (int off = 1; off < 64; off <<= 1) p += __shfl_xor(p, off);
        best = fmaxf(best, p);
    }
    if (lane == 0) smax[wid] = best;
    __syncthreads();
    if (tid == 0)
        resc[b] = fmaxf(fmaxf(smax[0], smax[1]), fmaxf(smax[2], smax[3]));
}

// ---------------------------------------------------------------------------
// final: top-64 over candidates (exact vals, tie: idx asc), softmax, gather V
// ---------------------------------------------------------------------------
__launch_bounds__(256)
__global__ void final_select(const int* __restrict__ cidx, const float* __restrict__ resc,
                             const int* __restrict__ cnt, const float* __restrict__ values,
                             float* __restrict__ out) {
    __shared__ float selw[64];
    __shared__ int   seli[64];
    const int tid = threadIdx.x;
    int nc = cnt[0];
    if (nc > CAP) nc = CAP;

    if (tid < 64) {
        const int lane = tid;
        float lv[16]; int li[16];
#pragma unroll
        for (int j = 0; j < 16; ++j) {
            int slot = lane + 64 * j;
            bool ok = slot < nc;
            lv[j] = ok ? resc[slot] : -__builtin_inff();
            li[j] = ok ? cidx[slot] : 0x7fffffff;
        }
        for (int it = 0; it < 64; ++it) {
            float bv = -__builtin_inff();
            int bg = 0x7fffffff, bj = 0;
#pragma unroll
            for (int j = 0; j < 16; ++j)
                if (lv[j] > bv || (lv[j] == bv && li[j] < bg)) { bv = lv[j]; bg = li[j]; bj = j; }
            int bcode = (lane << 4) | bj;
#pragma unroll
            for (int off = 1; off < 64; off <<= 1) {
                float ov = __shfl_xor(bv, off);
                int   og = __shfl_xor(bg, off);
                int   oc = __shfl_xor(bcode, off);
                if (ov > bv || (ov == bv && og < bg)) { bv = ov; bg = og; bcode = oc; }
            }
            if ((bcode >> 4) == lane) {
                int wj = bcode & 15;
#pragma unroll
                for (int j = 0; j < 16; ++j) if (j == wj) lv[j] = -__builtin_inff();
            }
            if (lane == 0) { selw[it] = bv; seli[it] = bg; }
        }
    }
    __syncthreads();

    if (tid < 64) {
        float x = selw[tid];
        float mx = x;
#pragma unroll
        for (int off = 1; off < 64; off <<= 1) mx = fmaxf(mx, __shfl_xor(mx, off));
        float e = expf(x - mx);
        float s = e;
#pragma unroll
        for (int off = 1; off < 64; off <<= 1) s += __shfl_xor(s, off);
        selw[tid] = e / s;
        out[DD + tid] = (float)seli[tid];
    }
    __syncthreads();

    for (int d = tid; d < DD; d += 256) {
        float accv = 0.f;
        for (int i = 0; i < 64; ++i)
            accv += selw[i] * values[(size_t)seli[i] * DD + d];
        out[d] = accv;
    }
}

// ---------------------------------------------------------------------------
extern "C" void kernel_launch(void* const* d_in, const int* in_sizes, int n_in,
                              void* d_out, int out_size, void* d_ws, size_t ws_size,
                              hipStream_t stream) {
    (void)in_sizes; (void)n_in; (void)out_size; (void)ws_size;
    const float* queries = (const float*)d_in[0];
    const float* keys    = (const float*)d_in[1];
    const float* values  = (const float*)d_in[2];
    const float* affine  = (const float*)d_in[3];
    float* out = (float*)d_out;
    char*  ws  = (char*)d_ws;

    unsigned short* qstage = (unsigned short*)(ws + QSTAGE_OFF);
    float* scores = (float*)(ws + SCORES_OFF);
    int*   cidx   = (int*)(ws + CIDX_OFF);
    float* resc   = (float*)(ws + RESC_OFF);
    int*   cnt    = (int*)(ws + CNT_OFF);
    unsigned int* hist = (unsigned int*)(ws + HIST_OFF);
    float* vlo    = (float*)(ws + VLO_OFF);

    hipFuncSetAttribute((const void*)scores_gemm,
                        hipFuncAttributeMaxDynamicSharedMemorySize, GEMM_LDS);

    prep_q<<<(NKK * NQ * 4) / 256, 256, 0, stream>>>(queries, affine, qstage);
    scores_gemm<<<MBLOCKS, 512, GEMM_LDS, stream>>>(keys, qstage, scores);
    zero_hist<<<8, 1024, 0, stream>>>(hist, cnt);
    hist_build<<<64, 256, 0, stream>>>(scores, hist);
    find_thresh<<<1, 1024, 0, stream>>>(hist, vlo);
    collect<<<200, 256, 0, stream>>>(scores, vlo, cidx, cnt);
    rescore<<<CAP, 256, 0, stream>>>(queries, affine, keys, cidx, cnt, resc);
    final_select<<<1, 256, 0, stream>>>(cidx, resc, cnt, values, out);
}